// Round 12
// baseline (332.614 us; speedup 1.0000x reference)
//
#include <hip/hip_runtime.h>
#include <math.h>

#define B_ 8
#define C_ 64
#define H_ 160
#define W_ 160
#define HW_ (H_*W_)

typedef _Float16 h2 __attribute__((ext_vector_type(2)));
typedef _Float16 h4 __attribute__((ext_vector_type(4)));
typedef _Float16 h8 __attribute__((ext_vector_type(8)));
typedef float f4v __attribute__((ext_vector_type(4)));
union H8u { h8 v; h2 h[4]; };

__device__ inline float fdot2(h2 a, h2 b, float c) {
    return __builtin_amdgcn_fdot2(a, b, c, false);
}

// q-weights are pre-scaled by log2(e) in qkv, so energy e' = e*log2e and
// p = exp2(e' - ESH2) == exp(e - 4). Constant shift cancels in the H/W softmax merge.
#define LOG2E 1.44269504088896f
#define ESH2  5.77078016355585f
#if __has_builtin(__builtin_amdgcn_exp2f)
#define EXP2F(x) __builtin_amdgcn_exp2f(x)
#else
#define EXP2F(x) exp2f(x)
#endif

static constexpr size_t N_PIX  = (size_t)B_*H_*W_;       // 204800
static constexpr size_t N_FULL = (size_t)B_*H_*W_*C_;    // 13107200
// ws (float units):
static constexpr size_t OFF_OUTH  = 0;                       // outH f16 [b][h][w][c]; o16 reuses (read-then-write per addr)
static constexpr size_t OFF_VROW  = N_FULL/2;                // v_row f16 [b][h][w][c]
static constexpr size_t OFF_QROW  = OFF_VROW + N_FULL/2;     // q_row f16 [b][h][w][8]
static constexpr size_t OFF_KROW  = OFF_QROW + N_PIX*4;
static constexpr size_t OFF_MH    = OFF_KROW + N_PIX*4;      // (unused now)
static constexpr size_t OFF_SH    = OFF_MH + N_PIX;
static constexpr size_t OFF_BNSUM = OFF_SH + N_PIX;
static constexpr size_t OFF_BNSQ  = OFF_BNSUM + 64;

// ---- qkv: x (NCHW fp32) -> q_row/k_row/v_row f16 (R11: MFMA V + QK) ----
__global__ __launch_bounds__(256,4) void qkv_kernel(
    const float* __restrict__ x,
    const float* __restrict__ wq, const float* __restrict__ bq,
    const float* __restrict__ wk, const float* __restrict__ bk,
    const float* __restrict__ wv, const float* __restrict__ bv,
    _Float16* __restrict__ qrow, _Float16* __restrict__ krow,
    _Float16* __restrict__ vrow)
{
    __shared__ __align__(16) _Float16 spool[10240];   // 20480 B: xsh -> vstage+qkstage
    _Float16 (*xsh)[72] = (_Float16 (*)[72])spool;    // 128 x 72 rows (18432 B used)

    const int tid = threadIdx.x;
    const int w0 = blockIdx.x * 32;
    const int h0 = blockIdx.y * 4;
    const int b  = blockIdx.z;

    const float* xb = x + (size_t)b*C_*HW_;
    for (int i = tid; i < 2048; i += 256) {
        int w4 = i & 7;
        int c  = ((i >> 3) & 7) | (((i >> 6) & 7) << 3);
        int hh = i >> 9;
        float4 v = *(const float4*)(xb + (size_t)c*HW_ + (size_t)(h0+hh)*W_ + w0 + w4*4);
        int pix = hh*32 + w4*4;
        xsh[pix+0][c] = (_Float16)v.x; xsh[pix+1][c] = (_Float16)v.y;
        xsh[pix+2][c] = (_Float16)v.z; xsh[pix+3][c] = (_Float16)v.w;
    }
    __syncthreads();

    const int lane = tid & 63;
    const int wid  = tid >> 6;
    const int n16  = lane & 15;
    const int kg   = lane >> 4;
    const int pb   = wid * 32;        // wave-private 32-pixel stripe

    // A fragments: af[sub][g] = x[pb+sub*16+n16][g*16+4kg .. +3]  (uniform per call)
    h4 af[2][4];
    #pragma unroll
    for (int sub = 0; sub < 2; sub++)
        #pragma unroll
        for (int g = 0; g < 4; g++)
            af[sub][g] = *(const h4*)&xsh[pb + sub*16 + n16][g*16 + 4*kg];

    // V: out[pix][co=g*16+n16] = x_g . wv_g; D col=channel, row=pixel
    f4v vacc[2][4];
    #pragma unroll
    for (int g = 0; g < 4; g++) {
        float4 wf = *(const float4*)(wv + (g*16 + n16)*16 + 4*kg);
        h4 bf; bf[0]=(_Float16)wf.x; bf[1]=(_Float16)wf.y;
               bf[2]=(_Float16)wf.z; bf[3]=(_Float16)wf.w;
        const float bb = bv[g*16 + n16];
        #pragma unroll
        for (int sub = 0; sub < 2; sub++) {
            f4v c = {bb, bb, bb, bb};
            vacc[sub][g] = __builtin_amdgcn_mfma_f32_16x16x16f16(af[sub][g], bf, c, 0, 0, 0);
        }
    }
    // QK: out n16 (0..7 = q scaled by log2e, 8..15 = k); group gq = (out&7)>>1.
    // 4 accumulated MFMAs per subtile; lane's B is zero except in MFMA gq.
    f4v qkacc[2];
    {
        const int out = n16;
        const int gq  = (out & 7) >> 1;
        const float sc = (out < 8) ? LOG2E : 1.0f;
        const float* wp = ((out < 8) ? wq + out*16 : wk + (out-8)*16) + 4*kg;
        float4 wf = *(const float4*)wp;
        h4 bfq; bfq[0]=(_Float16)(wf.x*sc); bfq[1]=(_Float16)(wf.y*sc);
                bfq[2]=(_Float16)(wf.z*sc); bfq[3]=(_Float16)(wf.w*sc);
        h4 bz;  bz[0]=(_Float16)0; bz[1]=(_Float16)0; bz[2]=(_Float16)0; bz[3]=(_Float16)0;
        const float bb = ((out < 8) ? bq[out] : bk[out-8]) * sc;
        #pragma unroll
        for (int sub = 0; sub < 2; sub++) {
            f4v c = {bb, bb, bb, bb};
            #pragma unroll
            for (int g = 0; g < 4; g++) {
                h4 bg = (gq == g) ? bfq : bz;
                c = __builtin_amdgcn_mfma_f32_16x16x16f16(af[sub][g], bg, c, 0, 0, 0);
            }
            qkacc[sub] = c;
        }
    }
    __syncthreads();   // all xsh reads done -> overlay

    _Float16* vst = spool;            // vstage [128 pix][64 ch] h16
    _Float16* qks = spool + 8192;     // qkstage [128 pix][16] h16
    #pragma unroll
    for (int sub = 0; sub < 2; sub++) {
        #pragma unroll
        for (int r = 0; r < 4; r++) {
            int pix = pb + sub*16 + 4*kg + r;       // D row = 4*(lane>>4)+r
            #pragma unroll
            for (int g = 0; g < 4; g++)
                vst[pix*64 + g*16 + n16] = (_Float16)vacc[sub][g][r];
            qks[pix*16 + n16] = (_Float16)qkacc[sub][r];
        }
    }
    __syncthreads();

    unsigned* vs32 = (unsigned*)spool;
    unsigned* qk32 = vs32 + 4096;
    unsigned* vrow32 = (unsigned*)vrow;
    for (int i = tid; i < 4096; i += 256) {
        int pix = i >> 5, cp = i & 31;
        size_t bp = ((size_t)b*H_ + h0 + (pix>>5))*W_ + w0 + (pix & 31);
        vrow32[bp*32 + cp] = vs32[i];
    }
    unsigned* qrow32 = (unsigned*)qrow;
    unsigned* krow32 = (unsigned*)krow;
    for (int i = tid; i < 1024; i += 256) {
        int pix = i >> 3, part = i & 7;
        size_t bp = ((size_t)b*H_ + h0 + (pix>>5))*W_ + w0 + (pix & 31);
        unsigned val = qk32[pix*8 + part];
        if (part < 4) qrow32[bp*4 + part]     = val;
        else          krow32[bp*4 + part - 4] = val;
    }
}

// ---- pass A: per (b,w,qtile) — H-attention (diag masked) ----
// R12: tile loop split into blocks (grid x5). One Pts buffer, 3 barriers, no
// pipeline. LDS ~23.8 KB -> 6 blocks/CU; 6400 blocks churn to hide latency.
// Consecutive blocks (same column, 5 tiles) share K/V reads via L2.
__global__ __launch_bounds__(256,4) void passA_kernel(
    const _Float16* __restrict__ qrow, const _Float16* __restrict__ krow,
    const _Float16* __restrict__ vrow,
    _Float16* __restrict__ outH, float* __restrict__ sH)
{
    __shared__ __align__(16) _Float16 pool[10240];     // v2s (20480 B) -> Pts (10240 B)
    __shared__ __align__(16) _Float16 q2h[32][8];
    __shared__ __align__(16) _Float16 k2h[160][8];
    __shared__ float psum2[2][32];                     // [j-half][q32]

    _Float16* v2s = pool;
    _Float16* Pts = pool;

    const int tid = threadIdx.x;
    const int bx  = blockIdx.x;
    const int t   = bx % 5;
    const int col = bx / 5;
    const int b = col / W_;
    const int w = col % W_;

    if (tid < 160) {
        size_t bp = ((size_t)b*H_ + tid)*W_ + w;
        *(int4*)&k2h[tid][0] = *(const int4*)(krow + bp*8);
        if (tid < 32) {
            size_t bq = ((size_t)b*H_ + t*32 + tid)*W_ + w;
            *(int4*)&q2h[tid][0] = *(const int4*)(qrow + bq*8);
        }
    }
    {
        const unsigned* vr32 = (const unsigned*)vrow;
        const int cp = tid & 31, hp0 = tid >> 5;
        #pragma unroll 5
        for (int it = 0; it < 10; it++) {
            int hp = hp0 + 8*it;                       // j-pair index
            int kt = hp >> 4, dqv = (hp >> 2) & 3, jj = 2*(hp & 3);
            size_t bp0 = ((size_t)b*H_ + 2*hp)*W_ + w;
            unsigned u0 = vr32[bp0*32 + cp];
            unsigned u1 = vr32[(bp0 + W_)*32 + cp];
            unsigned e  = __builtin_amdgcn_perm(u1, u0, 0x05040100);
            unsigned o  = __builtin_amdgcn_perm(u1, u0, 0x07060302);
            int base = ((kt*4 + dqv)*64 + 2*cp)*8 + jj;
            *(unsigned*)&v2s[base]     = e;
            *(unsigned*)&v2s[base + 8] = o;
        }
    }
    __syncthreads();

    const int lane = tid & 63;
    const int wid  = tid >> 6;
    const int cM   = wid*16 + (lane & 15);
    const int m_   = lane & 15;
    const int dq   = lane >> 4;
    const int n16  = lane & 15;     // q within subtile
    const int kg   = lane >> 4;     // k-group / D row group
    const int qs   = wid & 1;       // q-subtile of the 32-q tile
    const int jt0  = (wid >> 1)*5;  // 5 j-tiles of 16

    // V MFMA B-fragments -> registers (v2s dead after this)
    h8 vfr[5];
    #pragma unroll
    for (int kt = 0; kt < 5; kt++)
        vfr[kt] = *(const h8*)&v2s[((kt*4 + dq)*64 + cM)*8];
    __syncthreads();    // pool becomes Pts

    // energy via MFMA -> Pts; E^T = K(16j x 8c) x Q^T(8c x 16q)
    {
        const int q32  = qs*16 + n16;
        const int qrw  = t*32 + q32;                // global q row (0..159)
        h4 qf = *(const h4*)&q2h[q32][(kg & 1)*4];
        if (kg >= 2) { qf[0]=(_Float16)0; qf[1]=(_Float16)0; qf[2]=(_Float16)0; qf[3]=(_Float16)0; }
        float psloc = 0.f;
        #pragma unroll
        for (int jj = 0; jj < 5; jj++) {
            const int jt = jt0 + jj;
            h4 kf = *(const h4*)&k2h[jt*16 + n16][(kg & 1)*4];
            f4v d = {0.f,0.f,0.f,0.f};
            d = __builtin_amdgcn_mfma_f32_16x16x16f16(kf, qf, d, 0, 0, 0);
            const int grp = (jt >> 1)*4 + (jt & 1)*2 + (kg >> 1);
            h4 pk;
            #pragma unroll
            for (int r = 0; r < 4; r++) {
                float p = EXP2F(d[r] - ESH2);
                if (jt*16 + kg*4 + r == qrw) p = 0.f;   // diag mask
                psloc += p;
                pk[r] = (_Float16)p;
            }
            *(h4*)&Pts[(grp*32 + q32)*8 + (kg & 1)*4] = pk;
        }
        psloc += __shfl_xor(psloc, 16);
        psloc += __shfl_xor(psloc, 32);
        if (kg == 0) psum2[wid >> 1][q32] = psloc;
    }
    __syncthreads();    // Pts/psum2 ready

    if (tid < 32)
        sH[((size_t)b*W_ + w)*H_ + t*32 + tid] = psum2[0][tid] + psum2[1][tid];

    f4v acc0 = {0.f,0.f,0.f,0.f}, acc1 = {0.f,0.f,0.f,0.f};
    #pragma unroll
    for (int kt = 0; kt < 5; kt++) {
        h8 a0  = *(const h8*)&Pts[((kt*4 + dq)*32 + m_)*8];
        h8 a1  = *(const h8*)&Pts[((kt*4 + dq)*32 + 16 + m_)*8];
        acc0 = __builtin_amdgcn_mfma_f32_16x16x32_f16(a0, vfr[kt], acc0, 0, 0, 0);
        acc1 = __builtin_amdgcn_mfma_f32_16x16x32_f16(a1, vfr[kt], acc1, 0, 0, 0);
    }
    #pragma unroll
    for (int r = 0; r < 4; r++) {
        int r0 = t*32 + dq*4 + r;       // C/D: col=lane&15, row=(lane>>4)*4+reg
        outH[(((size_t)b*H_ + r0     )*W_ + w)*64 + cM] = (_Float16)acc0[r];
        outH[(((size_t)b*H_ + r0 + 16)*W_ + w)*64 + cM] = (_Float16)acc1[r];
    }
}

// ---- pass B: per (b,h,qtile) — W-attention + merge + w1d conv + BN partials ----
// R12 split. o16 output SHARES the outH buffer (outHio): each (row,tile,c) address
// is read (prefetch) then written by exactly ONE block -> race-free; vrow is now
// never overwritten (restrict ok).
__global__ __launch_bounds__(256,4) void passB_kernel(
    const _Float16* __restrict__ qrow, const _Float16* __restrict__ krow,
    const _Float16* __restrict__ vrow,
    const float* __restrict__ gamma, const float* __restrict__ w1d,
    _Float16* outHio,                 // read outH, write o16 (same addresses)
    const float* __restrict__ sH,
    float* __restrict__ bnsum, float* __restrict__ bnsq)
{
    __shared__ __align__(16) _Float16 pool[10240];     // v2s -> Pts[0..5120) + stageh[5120..7680)
    __shared__ __align__(16) _Float16 q2h[32][8];
    __shared__ __align__(16) _Float16 k2h[160][8];
    __shared__ float sHrow[32];
    __shared__ float psum2[2][32];

    _Float16* v2s = pool;
    _Float16* Pts = pool;
    _Float16* stageh = pool + 5120;

    const int tid = threadIdx.x;
    const int bx  = blockIdx.x;
    const int t   = bx % 5;
    const int row = bx / 5;
    const int b = row / H_;
    const int h = row % H_;
    const float gam = gamma[0];

    const int lane = tid & 63;
    const int wid  = tid >> 6;
    const int cM   = wid*16 + (lane & 15);
    const int m_   = lane & 15;
    const int dq   = lane >> 4;
    const int n16  = lane & 15;
    const int kg   = lane >> 4;
    const int qs   = wid & 1;
    const int jt0  = (wid >> 1)*5;

    // w1d B-fragment for 16x16x16 MFMA: lane holds B[k=4*dq+i][n=m_]
    h4 w1f;
    {
        float4 wv4 = *(const float4*)(w1d + cM*16 + 4*dq);
        w1f[0] = (_Float16)wv4.x; w1f[1] = (_Float16)wv4.y;
        w1f[2] = (_Float16)wv4.z; w1f[3] = (_Float16)wv4.w;
    }

    const size_t rowbase = ((size_t)b*H_ + h)*W_;
    if (tid < 160) {
        size_t bp = rowbase + tid;
        *(int4*)&k2h[tid][0] = *(const int4*)(krow + bp*8);
        if (tid < 32) {
            size_t bq = rowbase + t*32 + tid;
            *(int4*)&q2h[tid][0] = *(const int4*)(qrow + bq*8);
            sHrow[tid] = sH[((size_t)b*W_ + t*32 + tid)*H_ + h];
        }
    }
    {
        const unsigned* vr32 = (const unsigned*)vrow;
        const int cp = tid & 31, wp0 = tid >> 5;
        #pragma unroll 5
        for (int it = 0; it < 10; it++) {
            int wp = wp0 + 8*it;
            int kt = wp >> 4, dqv = (wp >> 2) & 3, jj = 2*(wp & 3);
            size_t bp0 = rowbase + 2*wp;
            unsigned u0 = vr32[bp0*32 + cp];
            unsigned u1 = vr32[(bp0 + 1)*32 + cp];
            unsigned e  = __builtin_amdgcn_perm(u1, u0, 0x05040100);
            unsigned o  = __builtin_amdgcn_perm(u1, u0, 0x07060302);
            int base = ((kt*4 + dqv)*64 + 2*cp)*8 + jj;
            *(unsigned*)&v2s[base]     = e;
            *(unsigned*)&v2s[base + 8] = o;
        }
    }
    __syncthreads();

    // V MFMA B-fragments -> registers
    h8 vfr[5];
    #pragma unroll
    for (int kt = 0; kt < 5; kt++)
        vfr[kt] = *(const h8*)&v2s[((kt*4 + dq)*64 + cM)*8];

    // outH prefetch (issue now; consumed after next barrier — loads cover energy)
    float oh0[4], oh1[4];
    #pragma unroll
    for (int r = 0; r < 4; r++) {
        int rw0 = t*32 + dq*4 + r;
        oh0[r] = (float)outHio[(rowbase + rw0     )*64 + cM];
        oh1[r] = (float)outHio[(rowbase + rw0 + 16)*64 + cM];
    }
    __syncthreads();    // v2s consumed -> pool becomes Pts/stageh

    // energy via MFMA -> Pts
    {
        const int q32 = qs*16 + n16;
        h4 qf = *(const h4*)&q2h[q32][(kg & 1)*4];
        if (kg >= 2) { qf[0]=(_Float16)0; qf[1]=(_Float16)0; qf[2]=(_Float16)0; qf[3]=(_Float16)0; }
        float psloc = 0.f;
        #pragma unroll
        for (int jj = 0; jj < 5; jj++) {
            const int jt = jt0 + jj;
            h4 kf = *(const h4*)&k2h[jt*16 + n16][(kg & 1)*4];
            f4v d = {0.f,0.f,0.f,0.f};
            d = __builtin_amdgcn_mfma_f32_16x16x16f16(kf, qf, d, 0, 0, 0);
            const int grp = (jt >> 1)*4 + (jt & 1)*2 + (kg >> 1);
            h4 pk;
            #pragma unroll
            for (int r = 0; r < 4; r++) {
                float p = EXP2F(d[r] - ESH2);
                psloc += p;
                pk[r] = (_Float16)p;
            }
            *(h4*)&Pts[(grp*32 + q32)*8 + (kg & 1)*4] = pk;
        }
        psloc += __shfl_xor(psloc, 16);
        psloc += __shfl_xor(psloc, 32);
        if (kg == 0) psum2[wid >> 1][q32] = psloc;
    }
    __syncthreads();    // Pts/psum2 ready

    // merge factor f = gamma/(sH+sW); lanes l<32 own row l, shfl broadcast
    const int rl_ = lane & 31;
    float fval = gam / (sHrow[rl_] + psum2[0][rl_] + psum2[1][rl_]);

    f4v acc0 = {0.f,0.f,0.f,0.f}, acc1 = {0.f,0.f,0.f,0.f};
    #pragma unroll
    for (int kt = 0; kt < 5; kt++) {
        h8 a0  = *(const h8*)&Pts[((kt*4 + dq)*32 + m_)*8];
        h8 a1  = *(const h8*)&Pts[((kt*4 + dq)*32 + 16 + m_)*8];
        acc0 = __builtin_amdgcn_mfma_f32_16x16x32_f16(a0, vfr[kt], acc0, 0, 0, 0);
        acc1 = __builtin_amdgcn_mfma_f32_16x16x32_f16(a1, vfr[kt], acc1, 0, 0, 0);
    }
    // merge -> wave-private stage (disjoint from Pts; Pts reads done per-wave,
    // stageh region [5120,7680) never overlaps Pts [0,5120))
    _Float16* st = &stageh[wid*640];
    #pragma unroll
    for (int r = 0; r < 4; r++) {
        int rl0 = dq*4 + r, rl1 = rl0 + 16;
        float f0 = __shfl(fval, rl0);
        float f1 = __shfl(fval, rl1);
        st[rl0*20 + m_] = (_Float16)((oh0[r] + acc0[r]) * f0);
        st[rl1*20 + m_] = (_Float16)((oh1[r] + acc1[r]) * f1);
    }
    // grouped w1d conv as MFMA: A = st (32pix x 16ch), B = w1f; wave-local
    h4 a0c = *(const h4*)&st[m_*20 + 4*dq];
    h4 a1c = *(const h4*)&st[(m_ + 16)*20 + 4*dq];
    f4v c0 = {0.f,0.f,0.f,0.f}, c1 = {0.f,0.f,0.f,0.f};
    c0 = __builtin_amdgcn_mfma_f32_16x16x16f16(a0c, w1f, c0, 0, 0, 0);
    c1 = __builtin_amdgcn_mfma_f32_16x16x16f16(a1c, w1f, c1, 0, 0, 0);
    float bnS = 0.f, bnS2 = 0.f;
    #pragma unroll
    for (int r = 0; r < 4; r++) {
        int pr0 = dq*4 + r, pr1 = pr0 + 16;
        float o0 = c0[r], o1 = c1[r];
        outHio[(rowbase + t*32 + pr0)*64 + cM] = (_Float16)o0;
        outHio[(rowbase + t*32 + pr1)*64 + cM] = (_Float16)o1;
        bnS  += o0 + o1;
        bnS2 += o0*o0 + o1*o1;
    }
    bnS  += __shfl_xor(bnS, 16);  bnS  += __shfl_xor(bnS, 32);
    bnS2 += __shfl_xor(bnS2, 16); bnS2 += __shfl_xor(bnS2, 32);
    if (dq == 0) {
        atomicAdd(&bnsum[cM], bnS);
        atomicAdd(&bnsq[cM],  bnS2);
    }
}

// ---- final: BN finalize (per-block, redundant) + normalize + residual + relu ----
__global__ __launch_bounds__(256) void final_kernel(
    const float* __restrict__ x, const _Float16* __restrict__ o16,
    const float* __restrict__ bnsum, const float* __restrict__ bnsq,
    const float* __restrict__ bn_w, const float* __restrict__ bn_b,
    float* __restrict__ out)
{
    __shared__ _Float16 olds[160*66];
    __shared__ float sc[64], sh[64];
    const int tid = threadIdx.x;
    const int b = blockIdx.x / H_, h = blockIdx.x % H_;
    if (tid < 64) {
        const float cnt = (float)(B_*H_*W_);
        float mean = bnsum[tid] / cnt;
        float var  = bnsq[tid] / cnt - mean*mean;
        float istd = rsqrtf(var + 1e-5f);
        float scl  = bn_w[tid] * istd;
        sc[tid] = scl;
        sh[tid] = bn_b[tid] - mean*scl;
    }
    const unsigned* op = (const unsigned*)(o16 + ((size_t)b*H_ + h)*W_*64);
    unsigned* ol32 = (unsigned*)olds;
    for (int i = tid; i < 5120; i += 256) {
        int w = i >> 5, c2 = i & 31;
        ol32[w*33 + c2] = op[i];
    }
    __syncthreads();
    const float* xr = x   + (size_t)b*C_*HW_ + (size_t)h*W_;
    float*       ob = out + (size_t)b*C_*HW_ + (size_t)h*W_;
    for (int i = tid; i < 64*160; i += 256) {
        int c = i / 160, w = i - c*160;
        float v = (float)olds[w*66 + c] * sc[c] + sh[c] + xr[(size_t)c*HW_ + w];
        ob[(size_t)c*HW_ + w] = fmaxf(v, 0.f);
    }
}

extern "C" void kernel_launch(void* const* d_in, const int* in_sizes, int n_in,
                              void* d_out, int out_size, void* d_ws, size_t ws_size,
                              hipStream_t stream)
{
    (void)in_sizes; (void)n_in; (void)out_size; (void)ws_size;
    const float* x     = (const float*)d_in[0];
    const float* wq    = (const float*)d_in[1];
    const float* bq    = (const float*)d_in[2];
    const float* wk    = (const float*)d_in[3];
    const float* bk    = (const float*)d_in[4];
    const float* wv    = (const float*)d_in[5];
    const float* bv    = (const float*)d_in[6];
    const float* gamma = (const float*)d_in[7];
    const float* w1d   = (const float*)d_in[8];
    const float* bn_w  = (const float*)d_in[9];
    const float* bn_b  = (const float*)d_in[10];

    float* ws = (float*)d_ws;
    _Float16* outH16 = (_Float16*)(ws + OFF_OUTH);   // outH, then o16 in-place
    _Float16* vrow   = (_Float16*)(ws + OFF_VROW);
    _Float16* qrow   = (_Float16*)(ws + OFF_QROW);
    _Float16* krow   = (_Float16*)(ws + OFF_KROW);
    float* sH    = ws + OFF_SH;
    float* bnsum = ws + OFF_BNSUM;
    float* bnsq  = ws + OFF_BNSQ;

    (void)hipMemsetAsync(bnsum, 0, 128*sizeof(float), stream);

    dim3 qgrid(W_/32, H_/4, B_);
    qkv_kernel<<<qgrid, 256, 0, stream>>>(x, wq, bq, wk, bk, wv, bv, qrow, krow, vrow);
    passA_kernel<<<B_*W_*5, 256, 0, stream>>>(qrow, krow, vrow, outH16, sH);
    passB_kernel<<<B_*H_*5, 256, 0, stream>>>(qrow, krow, vrow, gamma, w1d,
                                              outH16, sH, bnsum, bnsq);
    final_kernel<<<B_*H_, 256, 0, stream>>>(x, outH16, bnsum, bnsq, bn_w, bn_b, (float*)d_out);
}

// Round 13
// 203.801 us; speedup vs baseline: 1.6321x; 1.6321x over previous
//
#include <hip/hip_runtime.h>
#include <math.h>

#define B_ 8
#define C_ 64
#define H_ 160
#define W_ 160
#define HW_ (H_*W_)

typedef _Float16 h2 __attribute__((ext_vector_type(2)));
typedef _Float16 h4 __attribute__((ext_vector_type(4)));
typedef _Float16 h8 __attribute__((ext_vector_type(8)));
typedef float f4v __attribute__((ext_vector_type(4)));
union H8u { h8 v; h2 h[4]; };

// q-weights are pre-scaled by log2(e) in qkv, so energy e' = e*log2e and
// p = exp2(e' - ESH2) == exp(e - 4). Constant shift cancels in the H/W softmax merge.
#define LOG2E 1.44269504088896f
#define ESH2  5.77078016355585f
#if __has_builtin(__builtin_amdgcn_exp2f)
#define EXP2F(x) __builtin_amdgcn_exp2f(x)
#else
#define EXP2F(x) exp2f(x)
#endif

static constexpr size_t N_PIX  = (size_t)B_*H_*W_;       // 204800
static constexpr size_t N_FULL = (size_t)B_*H_*W_*C_;    // 13107200
// ws (float units):
static constexpr size_t OFF_OUTH  = 0;                       // outH f16 [b][h][w][c]
static constexpr size_t OFF_VROW  = N_FULL/2;                // v_row f16 [b][h][w][c]; o16 aliases
static constexpr size_t OFF_QROW  = OFF_VROW + N_FULL/2;     // q_row f16 [b][h][w][8]
static constexpr size_t OFF_KROW  = OFF_QROW + N_PIX*4;
static constexpr size_t OFF_MH    = OFF_KROW + N_PIX*4;      // (unused now)
static constexpr size_t OFF_SH    = OFF_MH + N_PIX;
static constexpr size_t OFF_BNSUM = OFF_SH + N_PIX;
static constexpr size_t OFF_BNSQ  = OFF_BNSUM + 64;

// ---- qkv: x (NCHW fp32) -> q_row/k_row/v_row f16 (R11: MFMA V + QK) ----
__global__ __launch_bounds__(256,4) void qkv_kernel(
    const float* __restrict__ x,
    const float* __restrict__ wq, const float* __restrict__ bq,
    const float* __restrict__ wk, const float* __restrict__ bk,
    const float* __restrict__ wv, const float* __restrict__ bv,
    _Float16* __restrict__ qrow, _Float16* __restrict__ krow,
    _Float16* __restrict__ vrow)
{
    __shared__ __align__(16) _Float16 spool[10240];   // 20480 B: xsh -> vstage+qkstage
    _Float16 (*xsh)[72] = (_Float16 (*)[72])spool;    // 128 x 72 rows (18432 B used)

    const int tid = threadIdx.x;
    const int w0 = blockIdx.x * 32;
    const int h0 = blockIdx.y * 4;
    const int b  = blockIdx.z;

    const float* xb = x + (size_t)b*C_*HW_;
    for (int i = tid; i < 2048; i += 256) {
        int w4 = i & 7;
        int c  = ((i >> 3) & 7) | (((i >> 6) & 7) << 3);
        int hh = i >> 9;
        float4 v = *(const float4*)(xb + (size_t)c*HW_ + (size_t)(h0+hh)*W_ + w0 + w4*4);
        int pix = hh*32 + w4*4;
        xsh[pix+0][c] = (_Float16)v.x; xsh[pix+1][c] = (_Float16)v.y;
        xsh[pix+2][c] = (_Float16)v.z; xsh[pix+3][c] = (_Float16)v.w;
    }
    __syncthreads();

    const int lane = tid & 63;
    const int wid  = tid >> 6;
    const int n16  = lane & 15;
    const int kg   = lane >> 4;
    const int pb   = wid * 32;        // wave-private 32-pixel stripe

    // A fragments: af[sub][g] = x[pb+sub*16+n16][g*16+4kg .. +3]  (uniform per call)
    h4 af[2][4];
    #pragma unroll
    for (int sub = 0; sub < 2; sub++)
        #pragma unroll
        for (int g = 0; g < 4; g++)
            af[sub][g] = *(const h4*)&xsh[pb + sub*16 + n16][g*16 + 4*kg];

    // V: out[pix][co=g*16+n16] = x_g . wv_g; D col=channel, row=pixel
    f4v vacc[2][4];
    #pragma unroll
    for (int g = 0; g < 4; g++) {
        float4 wf = *(const float4*)(wv + (g*16 + n16)*16 + 4*kg);
        h4 bf; bf[0]=(_Float16)wf.x; bf[1]=(_Float16)wf.y;
               bf[2]=(_Float16)wf.z; bf[3]=(_Float16)wf.w;
        const float bb = bv[g*16 + n16];
        #pragma unroll
        for (int sub = 0; sub < 2; sub++) {
            f4v c = {bb, bb, bb, bb};
            vacc[sub][g] = __builtin_amdgcn_mfma_f32_16x16x16f16(af[sub][g], bf, c, 0, 0, 0);
        }
    }
    // QK: out n16 (0..7 = q scaled by log2e, 8..15 = k); group gq = (out&7)>>1.
    // 4 accumulated MFMAs per subtile; lane's B is zero except in MFMA gq.
    f4v qkacc[2];
    {
        const int out = n16;
        const int gq  = (out & 7) >> 1;
        const float sc = (out < 8) ? LOG2E : 1.0f;
        const float* wp = ((out < 8) ? wq + out*16 : wk + (out-8)*16) + 4*kg;
        float4 wf = *(const float4*)wp;
        h4 bfq; bfq[0]=(_Float16)(wf.x*sc); bfq[1]=(_Float16)(wf.y*sc);
                bfq[2]=(_Float16)(wf.z*sc); bfq[3]=(_Float16)(wf.w*sc);
        h4 bz;  bz[0]=(_Float16)0; bz[1]=(_Float16)0; bz[2]=(_Float16)0; bz[3]=(_Float16)0;
        const float bb = ((out < 8) ? bq[out] : bk[out-8]) * sc;
        #pragma unroll
        for (int sub = 0; sub < 2; sub++) {
            f4v c = {bb, bb, bb, bb};
            #pragma unroll
            for (int g = 0; g < 4; g++) {
                h4 bg = (gq == g) ? bfq : bz;
                c = __builtin_amdgcn_mfma_f32_16x16x16f16(af[sub][g], bg, c, 0, 0, 0);
            }
            qkacc[sub] = c;
        }
    }
    __syncthreads();   // all xsh reads done -> overlay

    _Float16* vst = spool;            // vstage [128 pix][64 ch] h16
    _Float16* qks = spool + 8192;     // qkstage [128 pix][16] h16
    #pragma unroll
    for (int sub = 0; sub < 2; sub++) {
        #pragma unroll
        for (int r = 0; r < 4; r++) {
            int pix = pb + sub*16 + 4*kg + r;       // D row = 4*(lane>>4)+r
            #pragma unroll
            for (int g = 0; g < 4; g++)
                vst[pix*64 + g*16 + n16] = (_Float16)vacc[sub][g][r];
            qks[pix*16 + n16] = (_Float16)qkacc[sub][r];
        }
    }
    __syncthreads();

    unsigned* vs32 = (unsigned*)spool;
    unsigned* qk32 = vs32 + 4096;
    unsigned* vrow32 = (unsigned*)vrow;
    for (int i = tid; i < 4096; i += 256) {
        int pix = i >> 5, cp = i & 31;
        size_t bp = ((size_t)b*H_ + h0 + (pix>>5))*W_ + w0 + (pix & 31);
        vrow32[bp*32 + cp] = vs32[i];
    }
    unsigned* qrow32 = (unsigned*)qrow;
    unsigned* krow32 = (unsigned*)krow;
    for (int i = tid; i < 1024; i += 256) {
        int pix = i >> 3, part = i & 7;
        size_t bp = ((size_t)b*H_ + h0 + (pix>>5))*W_ + w0 + (pix & 31);
        unsigned val = qk32[pix*8 + part];
        if (part < 4) qrow32[bp*4 + part]     = val;
        else          krow32[bp*4 + part - 4] = val;
    }
}

// ---- pass A: per (b,w) column — H-attention (diag masked) ----
// R13 = R11 structure (5-tile loop, Pts[2] double-buffer, 1 barrier/tile) with
// v2s LDS staging DELETED: each lane loads its 40 V-halves (vfr[kt][e] =
// V[pix kt*32+dq*8+e][ch cM]) straight from global — removes 40 perms + 40 LDS
// writes (R12 showed ~1.5M bank conflicts live there) + 5 b128 reads + a barrier.
__global__ __launch_bounds__(256,4) void passA_kernel(
    const _Float16* __restrict__ qrow, const _Float16* __restrict__ krow,
    const _Float16* __restrict__ vrow,
    _Float16* __restrict__ outH, float* __restrict__ sH)
{
    __shared__ __align__(16) _Float16 pool[10240];     // Pts[2] (20480 B)
    __shared__ __align__(16) _Float16 q2h[160][8];
    __shared__ __align__(16) _Float16 k2h[160][8];
    __shared__ float psum2[2][2][32];                  // [buf][j-half][q32]

    const int tid = threadIdx.x;
    const int b = blockIdx.x / W_;
    const int w = blockIdx.x % W_;

    const int lane = tid & 63;
    const int wid  = tid >> 6;
    const int cM   = wid*16 + (lane & 15);
    const int m_   = lane & 15;
    const int dq   = lane >> 4;
    const int n16  = lane & 15;     // q within subtile
    const int kg   = lane >> 4;     // k-group / D row group
    const int qs   = wid & 1;       // q-subtile of the 32-q tile
    const int jt0  = (wid >> 1)*5;  // 5 j-tiles of 16

    if (tid < 160) {
        size_t bp = ((size_t)b*H_ + tid)*W_ + w;
        *(int4*)&q2h[tid][0] = *(const int4*)(qrow + bp*8);
        *(int4*)&k2h[tid][0] = *(const int4*)(krow + bp*8);
    }
    // V MFMA B-fragments direct from global (column pixels)
    h8 vfr[5];
    #pragma unroll
    for (int kt = 0; kt < 5; kt++)
        #pragma unroll
        for (int e = 0; e < 8; e++)
            vfr[kt][e] = vrow[(((size_t)b*H_ + kt*32 + dq*8 + e)*W_ + w)*64 + cM];
    __syncthreads();    // q2h/k2h ready (vfr loads drained by barrier's vmcnt(0))

    for (int t = 0; t <= 5; t++) {
        if (t <= 4) {                                   // energy(t) via MFMA -> Pts[t&1]
            _Float16* Pts = pool + (t & 1)*5120;
            const int q32  = qs*16 + n16;
            const int qrw  = t*32 + q32;                // global q row (0..159)
            h4 qf = *(const h4*)&q2h[qrw][(kg & 1)*4];
            if (kg >= 2) { qf[0]=(_Float16)0; qf[1]=(_Float16)0; qf[2]=(_Float16)0; qf[3]=(_Float16)0; }
            float psloc = 0.f;
            #pragma unroll
            for (int jj = 0; jj < 5; jj++) {
                const int jt = jt0 + jj;
                h4 kf = *(const h4*)&k2h[jt*16 + n16][(kg & 1)*4];
                f4v d = {0.f,0.f,0.f,0.f};
                d = __builtin_amdgcn_mfma_f32_16x16x16f16(kf, qf, d, 0, 0, 0);
                const int grp = (jt >> 1)*4 + (jt & 1)*2 + (kg >> 1);
                h4 pk;
                #pragma unroll
                for (int r = 0; r < 4; r++) {
                    float p = EXP2F(d[r] - ESH2);
                    if (jt*16 + kg*4 + r == qrw) p = 0.f;   // diag mask
                    psloc += p;
                    pk[r] = (_Float16)p;
                }
                *(h4*)&Pts[(grp*32 + q32)*8 + (kg & 1)*4] = pk;
            }
            psloc += __shfl_xor(psloc, 16);
            psloc += __shfl_xor(psloc, 32);
            if (kg == 0) psum2[t & 1][wid >> 1][q32] = psloc;
        }
        if (t >= 1) {                                   // MFMA(t-1) <- Pts[(t-1)&1]
            if (tid < 32) {                             // publish sH for tile t-1
                sH[((size_t)b*W_ + w)*H_ + (t-1)*32 + tid] =
                    psum2[(t-1) & 1][0][tid] + psum2[(t-1) & 1][1][tid];
            }
            const _Float16* Pts = pool + ((t-1) & 1)*5120;
            f4v acc0 = {0.f,0.f,0.f,0.f}, acc1 = {0.f,0.f,0.f,0.f};
            #pragma unroll
            for (int kt = 0; kt < 5; kt++) {
                h8 a0  = *(const h8*)&Pts[((kt*4 + dq)*32 + m_)*8];
                h8 a1  = *(const h8*)&Pts[((kt*4 + dq)*32 + 16 + m_)*8];
                acc0 = __builtin_amdgcn_mfma_f32_16x16x32_f16(a0, vfr[kt], acc0, 0, 0, 0);
                acc1 = __builtin_amdgcn_mfma_f32_16x16x32_f16(a1, vfr[kt], acc1, 0, 0, 0);
            }
            #pragma unroll
            for (int r = 0; r < 4; r++) {
                int r0 = (t-1)*32 + dq*4 + r;   // C/D: col=lane&15, row=(lane>>4)*4+reg
                outH[(((size_t)b*H_ + r0     )*W_ + w)*64 + cM] = (_Float16)acc0[r];
                outH[(((size_t)b*H_ + r0 + 16)*W_ + w)*64 + cM] = (_Float16)acc1[r];
            }
        }
        if (t <= 4) __syncthreads();    // Pts/psum2[t&1] published; prior reads done
    }
}

// ---- pass B: per (b,h) row — W-attention + merge + w1d conv + BN partials ----
// R13: v2s staging deleted (direct vfr loads, row pixels). o16 aliases vrow;
// safe: all vfr loads drain at the staging barrier, o16 stores happen after.
__global__ __launch_bounds__(256,4) void passB_kernel(
    const _Float16* __restrict__ qrow, const _Float16* __restrict__ krow,
    const _Float16* vrow,                 // aliases o16 — no restrict
    const float* __restrict__ gamma, const float* __restrict__ w1d,
    const _Float16* __restrict__ outH, const float* __restrict__ sH,
    _Float16* o16, float* __restrict__ bnsum, float* __restrict__ bnsq)
{
    __shared__ __align__(16) _Float16 pool[10240];     // Pts[2]
    __shared__ __align__(16) _Float16 stageh[4*32*20]; // 5120 B, wave-private stripes
    __shared__ __align__(16) _Float16 q2h[160][8];
    __shared__ __align__(16) _Float16 k2h[160][8];
    __shared__ float sHrow[160];
    __shared__ float psum2[2][2][32];

    const int tid = threadIdx.x;
    const int b = blockIdx.x / H_;
    const int h = blockIdx.x % H_;
    const float gam = gamma[0];

    const int lane = tid & 63;
    const int wid  = tid >> 6;
    const int cM   = wid*16 + (lane & 15);
    const int m_   = lane & 15;
    const int dq   = lane >> 4;
    const int n16  = lane & 15;
    const int kg   = lane >> 4;
    const int qs   = wid & 1;
    const int jt0  = (wid >> 1)*5;

    // w1d B-fragment for 16x16x16 MFMA: lane holds B[k=4*dq+i][n=m_]
    h4 w1f;
    {
        float4 wv4 = *(const float4*)(w1d + cM*16 + 4*dq);
        w1f[0] = (_Float16)wv4.x; w1f[1] = (_Float16)wv4.y;
        w1f[2] = (_Float16)wv4.z; w1f[3] = (_Float16)wv4.w;
    }

    const size_t rowbase = ((size_t)b*H_ + h)*W_;
    if (tid < 160) {
        size_t bp = rowbase + tid;
        *(int4*)&q2h[tid][0] = *(const int4*)(qrow + bp*8);
        *(int4*)&k2h[tid][0] = *(const int4*)(krow + bp*8);
        sHrow[tid] = sH[((size_t)b*W_ + tid)*H_ + h];
    }
    // V MFMA B-fragments direct from global (row pixels); must complete before
    // any o16 store (guaranteed: barrier below drains vmcnt)
    h8 vfr[5];
    #pragma unroll
    for (int kt = 0; kt < 5; kt++)
        #pragma unroll
        for (int e = 0; e < 8; e++)
            vfr[kt][e] = vrow[(rowbase + kt*32 + dq*8 + e)*64 + cM];
    __syncthreads();    // q2h/k2h/sHrow ready; vfr loads drained

    float bnS = 0.f, bnS2 = 0.f;

    for (int t = 0; t <= 5; t++) {
        // prefetch outH for tile (t-1) — consumed after energy(t)+MFMA, long cover
        float oh0[4], oh1[4];
        if (t >= 1) {
            #pragma unroll
            for (int r = 0; r < 4; r++) {
                int rw0 = (t-1)*32 + dq*4 + r;
                oh0[r] = (float)outH[(rowbase + rw0     )*64 + cM];
                oh1[r] = (float)outH[(rowbase + rw0 + 16)*64 + cM];
            }
        }
        if (t <= 4) {                                   // energy(t) via MFMA -> Pts[t&1]
            _Float16* Pts = pool + (t & 1)*5120;
            const int q32 = qs*16 + n16;
            const int qrw = t*32 + q32;
            h4 qf = *(const h4*)&q2h[qrw][(kg & 1)*4];
            if (kg >= 2) { qf[0]=(_Float16)0; qf[1]=(_Float16)0; qf[2]=(_Float16)0; qf[3]=(_Float16)0; }
            float psloc = 0.f;
            #pragma unroll
            for (int jj = 0; jj < 5; jj++) {
                const int jt = jt0 + jj;
                h4 kf = *(const h4*)&k2h[jt*16 + n16][(kg & 1)*4];
                f4v d = {0.f,0.f,0.f,0.f};
                d = __builtin_amdgcn_mfma_f32_16x16x16f16(kf, qf, d, 0, 0, 0);
                const int grp = (jt >> 1)*4 + (jt & 1)*2 + (kg >> 1);
                h4 pk;
                #pragma unroll
                for (int r = 0; r < 4; r++) {
                    float p = EXP2F(d[r] - ESH2);
                    psloc += p;
                    pk[r] = (_Float16)p;
                }
                *(h4*)&Pts[(grp*32 + q32)*8 + (kg & 1)*4] = pk;
            }
            psloc += __shfl_xor(psloc, 16);
            psloc += __shfl_xor(psloc, 32);
            if (kg == 0) psum2[t & 1][wid >> 1][q32] = psloc;
        }
        if (t >= 1) {                                   // MFMA(t-1) + merge + conv
            const int tp = t - 1;
            const _Float16* Pts = pool + (tp & 1)*5120;
            // f for the 32 rows of tile tp (lanes l<32 compute f[l]; shfl broadcast)
            const int rl_ = lane & 31;
            float fval = gam / (sHrow[tp*32 + rl_]
                                + psum2[tp & 1][0][rl_] + psum2[tp & 1][1][rl_]);
            f4v acc0 = {0.f,0.f,0.f,0.f}, acc1 = {0.f,0.f,0.f,0.f};
            #pragma unroll
            for (int kt = 0; kt < 5; kt++) {
                h8 a0  = *(const h8*)&Pts[((kt*4 + dq)*32 + m_)*8];
                h8 a1  = *(const h8*)&Pts[((kt*4 + dq)*32 + 16 + m_)*8];
                acc0 = __builtin_amdgcn_mfma_f32_16x16x32_f16(a0, vfr[kt], acc0, 0, 0, 0);
                acc1 = __builtin_amdgcn_mfma_f32_16x16x32_f16(a1, vfr[kt], acc1, 0, 0, 0);
            }
            // merge -> wave-private stage, f16 — no barrier needed
            _Float16* st = &stageh[wid*640];
            #pragma unroll
            for (int r = 0; r < 4; r++) {
                int rl0 = dq*4 + r, rl1 = rl0 + 16;
                float f0 = __shfl(fval, rl0);
                float f1 = __shfl(fval, rl1);
                st[rl0*20 + m_] = (_Float16)((oh0[r] + acc0[r]) * f0);
                st[rl1*20 + m_] = (_Float16)((oh1[r] + acc1[r]) * f1);
            }
            // grouped w1d conv as MFMA: A = st (32pix x 16ch), B = w1f; wave-local
            h4 a0c = *(const h4*)&st[m_*20 + 4*dq];
            h4 a1c = *(const h4*)&st[(m_ + 16)*20 + 4*dq];
            f4v c0 = {0.f,0.f,0.f,0.f}, c1 = {0.f,0.f,0.f,0.f};
            c0 = __builtin_amdgcn_mfma_f32_16x16x16f16(a0c, w1f, c0, 0, 0, 0);
            c1 = __builtin_amdgcn_mfma_f32_16x16x16f16(a1c, w1f, c1, 0, 0, 0);
            #pragma unroll
            for (int r = 0; r < 4; r++) {
                int pr0 = dq*4 + r, pr1 = pr0 + 16;
                float o0 = c0[r], o1 = c1[r];
                o16[(rowbase + tp*32 + pr0)*64 + cM] = (_Float16)o0;
                o16[(rowbase + tp*32 + pr1)*64 + cM] = (_Float16)o1;
                bnS  += o0 + o1;
                bnS2 += o0*o0 + o1*o1;
            }
        }
        if (t <= 4) __syncthreads();    // Pts/psum2[t&1] published; prior reads done
    }
    bnS  += __shfl_xor(bnS, 16);  bnS  += __shfl_xor(bnS, 32);
    bnS2 += __shfl_xor(bnS2, 16); bnS2 += __shfl_xor(bnS2, 32);
    if (dq == 0) {
        atomicAdd(&bnsum[cM], bnS);
        atomicAdd(&bnsq[cM],  bnS2);
    }
}

// ---- final: BN finalize (per-block, redundant) + normalize + residual + relu ----
__global__ __launch_bounds__(256) void final_kernel(
    const float* __restrict__ x, const _Float16* __restrict__ o16,
    const float* __restrict__ bnsum, const float* __restrict__ bnsq,
    const float* __restrict__ bn_w, const float* __restrict__ bn_b,
    float* __restrict__ out)
{
    __shared__ _Float16 olds[160*66];
    __shared__ float sc[64], sh[64];
    const int tid = threadIdx.x;
    const int b = blockIdx.x / H_, h = blockIdx.x % H_;
    if (tid < 64) {
        const float cnt = (float)(B_*H_*W_);
        float mean = bnsum[tid] / cnt;
        float var  = bnsq[tid] / cnt - mean*mean;
        float istd = rsqrtf(var + 1e-5f);
        float scl  = bn_w[tid] * istd;
        sc[tid] = scl;
        sh[tid] = bn_b[tid] - mean*scl;
    }
    const unsigned* op = (const unsigned*)(o16 + ((size_t)b*H_ + h)*W_*64);
    unsigned* ol32 = (unsigned*)olds;
    for (int i = tid; i < 5120; i += 256) {
        int w = i >> 5, c2 = i & 31;
        ol32[w*33 + c2] = op[i];
    }
    __syncthreads();
    const float* xr = x   + (size_t)b*C_*HW_ + (size_t)h*W_;
    float*       ob = out + (size_t)b*C_*HW_ + (size_t)h*W_;
    for (int i = tid; i < 64*160; i += 256) {
        int c = i / 160, w = i - c*160;
        float v = (float)olds[w*66 + c] * sc[c] + sh[c] + xr[(size_t)c*HW_ + w];
        ob[(size_t)c*HW_ + w] = fmaxf(v, 0.f);
    }
}

extern "C" void kernel_launch(void* const* d_in, const int* in_sizes, int n_in,
                              void* d_out, int out_size, void* d_ws, size_t ws_size,
                              hipStream_t stream)
{
    (void)in_sizes; (void)n_in; (void)out_size; (void)ws_size;
    const float* x     = (const float*)d_in[0];
    const float* wq    = (const float*)d_in[1];
    const float* bq    = (const float*)d_in[2];
    const float* wk    = (const float*)d_in[3];
    const float* bk    = (const float*)d_in[4];
    const float* wv    = (const float*)d_in[5];
    const float* bv    = (const float*)d_in[6];
    const float* gamma = (const float*)d_in[7];
    const float* w1d   = (const float*)d_in[8];
    const float* bn_w  = (const float*)d_in[9];
    const float* bn_b  = (const float*)d_in[10];

    float* ws = (float*)d_ws;
    _Float16* outH16 = (_Float16*)(ws + OFF_OUTH);
    _Float16* vrow   = (_Float16*)(ws + OFF_VROW);
    _Float16* qrow   = (_Float16*)(ws + OFF_QROW);
    _Float16* krow   = (_Float16*)(ws + OFF_KROW);
    float* sH    = ws + OFF_SH;
    float* bnsum = ws + OFF_BNSUM;
    float* bnsq  = ws + OFF_BNSQ;
    _Float16* o16 = vrow;   // alias: each passB block overwrites only the row it consumed

    (void)hipMemsetAsync(bnsum, 0, 128*sizeof(float), stream);

    dim3 qgrid(W_/32, H_/4, B_);
    qkv_kernel<<<qgrid, 256, 0, stream>>>(x, wq, bq, wk, bk, wv, bv, qrow, krow, vrow);
    passA_kernel<<<B_*W_, 256, 0, stream>>>(qrow, krow, vrow, outH16, sH);
    passB_kernel<<<B_*H_, 256, 0, stream>>>(qrow, krow, vrow, gamma, w1d,
                                            outH16, sH, o16, bnsum, bnsq);
    final_kernel<<<B_*H_, 256, 0, stream>>>(x, o16, bnsum, bnsq, bn_w, bn_b, (float*)d_out);
}